// Round 1
// baseline (2183.882 us; speedup 1.0000x reference)
//
#include <hip/hip_runtime.h>
#include <hip/hip_cooperative_groups.h>
#include <math.h>

namespace cg = cooperative_groups;

#define NV 196608
#define NDEG 9
#define NC 64
#define NK 8
#define TILE 64
#define NBLK (NV / TILE)   // 3072
#define SLOT ((size_t)NV * NC)
// fused cooperative config: 512 blocks x 256 threads, 6 tiles/block
#define FBLK 512
#define FTIL 6
static constexpr float EPS = 1e-5f;

typedef __attribute__((ext_vector_type(8))) short bf16x8;
typedef __attribute__((ext_vector_type(4))) short bf16x4;
typedef __attribute__((ext_vector_type(4))) float f32x4;
typedef int   i32x4u __attribute__((ext_vector_type(4), aligned(4)));
typedef float f32x4u __attribute__((ext_vector_type(4), aligned(4)));

// float -> bf16 bits, round-to-nearest-even (finite inputs)
__device__ __forceinline__ short f2bf(float f) {
    unsigned u = __float_as_uint(f);
    unsigned r = (u + 0x7fffu + ((u >> 16) & 1u)) >> 16;
    return (short)r;
}
__device__ __forceinline__ float bf2f(short h) {
    return __uint_as_float(((unsigned)(unsigned short)h) << 16);
}

// exact mish: h * tanh(softplus(h)); tanh(ln(p)) = (p^2-1)/(p^2+1), p = 1+e^h
__device__ __forceinline__ float mish_f(float h) {
    float t = __expf(fminf(h, 20.f));
    float p = 1.f + t;
    float p2 = p * p;
    return h * ((p2 - 1.f) / (p2 + 1.f));
}

// LDS tile address: row-stride 64 shorts, 8-short chunks XOR-swizzled.
// Proven 0-conflict layout (round 6 of prior session).
#define LDSOFF(r, c) ((r) * 64 + (((c) ^ ((r) & 7)) * 8))

// ===========================================================================
// FUSED persistent cooperative kernel: stats + BN/Mish + 7 Chebyshev steps +
// einsum accumulation, with grid.sync() between producer phases.
//  - each block owns FTIL=6 consecutive 64-row tiles; acc[6][4] f32x4 in regs
//  - per step: produce tile t+1 (gathers) issued BEFORE MFMA of tile t
//    (double-buffered LDS A-stage) so MFMA runs in the gather-latency shadow
//  - slot 7 never written to global (consumed from LDS only)
//  - launch_bounds(256,2): VGPR<=256 -> >=2 blocks/CU -> 512 blocks co-resident
// ===========================================================================
__global__ void __launch_bounds__(256, 2) fused_cheb(
    const float* __restrict__ x, const int* __restrict__ cols,
    const float* __restrict__ vals, const float* __restrict__ gamma,
    const float* __restrict__ beta, const float* __restrict__ weight,
    const float* __restrict__ bias, float* __restrict__ stats,
    unsigned short* __restrict__ Wb, unsigned short* __restrict__ basis,
    float* __restrict__ out)
{
    cg::grid_group grid = cg::this_grid();

    __shared__ __align__(16) short Al[2][4096];   // 2 x 8 KB A-tile staging
    __shared__ __align__(16) short Wl[4096];      // 8 KB W_k staging

    const int tid  = threadIdx.x;
    const int lane = tid & 63;
    const int wave = tid >> 6;
    const int gtid = blockIdx.x * 256 + tid;
    const int c8 = lane & 7, rg = lane >> 3;      // produce mapping
    const int m16 = lane & 15, qq = lane >> 4;    // MFMA fragment mapping
    const int rA = tid >> 3, cA = tid & 7;        // W staging mapping
    const int bv0 = blockIdx.x * (FTIL * TILE);   // first vertex of this block

    // ---- phase W: weight transpose -> Wb[k][o][i] (bf16), blocks 0..127 ----
    if (gtid < 32768) {
        int i = gtid & 63, o = (gtid >> 6) & 63, k = gtid >> 12;
        Wb[gtid] = (unsigned short)f2bf(weight[k * 4096 + i * 64 + o]);
    }

    // ---- phase S: batch stats (grid-stride, block reduce, atomicAdd) ----
    {
        const float4* x4 = (const float4*)x;
        float4 s = {0.f, 0.f, 0.f, 0.f}, ss = {0.f, 0.f, 0.f, 0.f};
        for (int i = gtid; i < NV * (NC / 4); i += FBLK * 256) {
            float4 v = x4[i];
            s.x += v.x; s.y += v.y; s.z += v.z; s.w += v.w;
            ss.x += v.x * v.x; ss.y += v.y * v.y; ss.z += v.z * v.z; ss.w += v.w * v.w;
        }
        float4* ls  = (float4*)&Al[0][0];          // 4 KB
        float4* lss = ((float4*)&Al[0][0]) + 256;  // 4 KB
        ls[tid] = s;
        lss[tid] = ss;
        __syncthreads();
        if (tid < 64) {
            int g = tid >> 2, comp = tid & 3;
            float a = 0.f, b = 0.f;
            #pragma unroll
            for (int k2 = 0; k2 < 16; ++k2) {
                float4 v1 = ls[k2 * 16 + g];
                float4 v2 = lss[k2 * 16 + g];
                a += (comp == 0) ? v1.x : (comp == 1) ? v1.y : (comp == 2) ? v1.z : v1.w;
                b += (comp == 0) ? v2.x : (comp == 1) ? v2.y : (comp == 2) ? v2.z : v2.w;
            }
            atomicAdd(&stats[tid], a);
            atomicAdd(&stats[64 + tid], b);
        }
    }
    __threadfence();
    grid.sync();
    __threadfence();

    // ---- BN coefficients for this thread's 8 channels (c8*8 .. c8*8+7) ----
    float sc[8], sh[8];
    #pragma unroll
    for (int q = 0; q < 8; ++q) {
        int ch = c8 * 8 + q;
        float mu = stats[ch] * (1.f / NV);
        float va = stats[64 + ch] * (1.f / NV) - mu * mu;
        float rs = rsqrtf(va + EPS);
        sc[q] = gamma[ch] * rs;
        sh[q] = beta[ch] - mu * sc[q];
    }

    f32x4 acc[FTIL][4];
    #pragma unroll
    for (int t = 0; t < FTIL; ++t)
        #pragma unroll
        for (int nt = 0; nt < 4; ++nt) acc[t][nt] = (f32x4){0.f, 0.f, 0.f, 0.f};

    auto stage_W = [&](int k) {
        const unsigned short* wp = Wb + k * 4096;
        *(bf16x8*)&Wl[LDSOFF(rA, cA)]      = *(const bf16x8*)(wp + rA * 64 + cA * 8);
        *(bf16x8*)&Wl[LDSOFF(rA + 32, cA)] = *(const bf16x8*)(wp + (rA + 32) * 64 + cA * 8);
    };

    // k=0 producer: BN + Mish from x (L3-resident after stats pass)
    auto produce_bn = [&](int t, int buf) {
        short* ap = &Al[buf][0];
        #pragma unroll
        for (int it = 0; it < 2; ++it) {
            int r = wave * 16 + it * 8 + rg;
            int v = bv0 + t * TILE + r;
            const float4* xr = (const float4*)(x + (size_t)v * NC + c8 * 8);
            float4 h0 = xr[0], h1 = xr[1];
            float m0 = mish_f(h0.x * sc[0] + sh[0]);
            float m1 = mish_f(h0.y * sc[1] + sh[1]);
            float m2 = mish_f(h0.z * sc[2] + sh[2]);
            float m3 = mish_f(h0.w * sc[3] + sh[3]);
            float m4 = mish_f(h1.x * sc[4] + sh[4]);
            float m5 = mish_f(h1.y * sc[5] + sh[5]);
            float m6 = mish_f(h1.z * sc[6] + sh[6]);
            float m7 = mish_f(h1.w * sc[7] + sh[7]);
            bf16x8 xb = { f2bf(m0), f2bf(m1), f2bf(m2), f2bf(m3),
                          f2bf(m4), f2bf(m5), f2bf(m6), f2bf(m7) };
            *(bf16x8*)(basis + (size_t)v * NC + c8 * 8) = xb;   // slot 0
            *(bf16x8*)&ap[LDSOFF(r, c8)] = xb;
        }
    };

    // k>=1 producer: one Chebyshev step (gather L@src, 2*s - prev)
    auto produce_ch = [&](int k, int t, int buf) {
        const unsigned short* src = basis + (size_t)(k - 1) * SLOT;
        const unsigned short* prv = basis + (size_t)(k >= 2 ? k - 2 : 0) * SLOT;
        unsigned short*       dst = basis + (size_t)k * SLOT;
        short* ap = &Al[buf][0];
        #pragma unroll
        for (int it = 0; it < 2; ++it) {
            int r = wave * 16 + it * 8 + rg;
            int v = bv0 + t * TILE + r;
            const int* cp = cols + v * NDEG;
            const float* vp = vals + v * NDEG;
            i32x4u c03 = *(const i32x4u*)cp;
            i32x4u c47 = *(const i32x4u*)(cp + 4);
            int    cl8 = cp[8];
            f32x4u a03 = *(const f32x4u*)vp;
            f32x4u a47 = *(const f32x4u*)(vp + 4);
            float  al8 = vp[8];

            int   cj[NDEG] = { c03[0], c03[1], c03[2], c03[3],
                               c47[0], c47[1], c47[2], c47[3], cl8 };
            float aj[NDEG] = { a03[0], a03[1], a03[2], a03[3],
                               a47[0], a47[1], a47[2], a47[3], al8 };

            bf16x8 g[NDEG];
            #pragma unroll
            for (int j = 0; j < NDEG; ++j)
                g[j] = *(const bf16x8*)(src + (size_t)cj[j] * NC + c8 * 8);

            float s[8] = {0.f, 0.f, 0.f, 0.f, 0.f, 0.f, 0.f, 0.f};
            #pragma unroll
            for (int j = 0; j < NDEG; ++j)
                #pragma unroll
                for (int q = 0; q < 8; ++q) s[q] += aj[j] * bf2f(g[j][q]);

            bf16x8 xb;
            if (k >= 2) {
                bf16x8 p = __builtin_nontemporal_load(
                               (const bf16x8*)(prv + (size_t)v * NC + c8 * 8));
                #pragma unroll
                for (int q = 0; q < 8; ++q) xb[q] = f2bf(2.f * s[q] - bf2f(p[q]));
            } else {
                #pragma unroll
                for (int q = 0; q < 8; ++q) xb[q] = f2bf(s[q]);
            }
            if (k < NK - 1)   // slot 7 consumed from LDS only
                *(bf16x8*)(dst + (size_t)v * NC + c8 * 8) = xb;
            *(bf16x8*)&ap[LDSOFF(r, c8)] = xb;
        }
    };

    // ---- phase C0: BN/Mish tiles + acc += x_0 @ W_0 ----
    stage_W(0);
    produce_bn(0, 0);
    #pragma unroll
    for (int t = 0; t < FTIL; ++t) {
        __syncthreads();
        if (t < FTIL - 1) produce_bn(t + 1, (t + 1) & 1);
        const short* ab = &Al[t & 1][0];
        bf16x8 a0 = *(const bf16x8*)&ab[LDSOFF(wave * 16 + m16, qq)];
        bf16x8 a1 = *(const bf16x8*)&ab[LDSOFF(wave * 16 + m16, qq + 4)];
        #pragma unroll
        for (int nt = 0; nt < 4; ++nt) {
            bf16x8 b0 = *(const bf16x8*)&Wl[LDSOFF(nt * 16 + m16, qq)];
            bf16x8 b1 = *(const bf16x8*)&Wl[LDSOFF(nt * 16 + m16, qq + 4)];
            acc[t][nt] = __builtin_amdgcn_mfma_f32_16x16x32_bf16(a0, b0, acc[t][nt], 0, 0, 0);
            acc[t][nt] = __builtin_amdgcn_mfma_f32_16x16x32_bf16(a1, b1, acc[t][nt], 0, 0, 0);
        }
    }

    // ---- phases C1..C7: Chebyshev step + acc += x_k @ W_k ----
    #pragma unroll 1
    for (int k = 1; k < NK; ++k) {
        __threadfence();     // publish slot k-1 writes (cross-XCD)
        grid.sync();
        __threadfence();     // acquire: invalidate stale cached lines
        stage_W(k);
        produce_ch(k, 0, 0);
        #pragma unroll
        for (int t = 0; t < FTIL; ++t) {
            __syncthreads();
            if (t < FTIL - 1) produce_ch(k, t + 1, (t + 1) & 1);
            const short* ab = &Al[t & 1][0];
            bf16x8 a0 = *(const bf16x8*)&ab[LDSOFF(wave * 16 + m16, qq)];
            bf16x8 a1 = *(const bf16x8*)&ab[LDSOFF(wave * 16 + m16, qq + 4)];
            #pragma unroll
            for (int nt = 0; nt < 4; ++nt) {
                bf16x8 b0 = *(const bf16x8*)&Wl[LDSOFF(nt * 16 + m16, qq)];
                bf16x8 b1 = *(const bf16x8*)&Wl[LDSOFF(nt * 16 + m16, qq + 4)];
                acc[t][nt] = __builtin_amdgcn_mfma_f32_16x16x32_bf16(a0, b0, acc[t][nt], 0, 0, 0);
                acc[t][nt] = __builtin_amdgcn_mfma_f32_16x16x32_bf16(a1, b1, acc[t][nt], 0, 0, 0);
            }
        }
    }

    // ---- epilogue: out = acc + bias ----
    #pragma unroll
    for (int t = 0; t < FTIL; ++t) {
        #pragma unroll
        for (int nt = 0; nt < 4; ++nt) {
            float bcol = bias[nt * 16 + m16];
            #pragma unroll
            for (int r4 = 0; r4 < 4; ++r4) {
                int vout = bv0 + t * TILE + wave * 16 + qq * 4 + r4;
                out[(size_t)vout * NC + nt * 16 + m16] = acc[t][nt][r4] + bcol;
            }
        }
    }
}

// ===========================================================================
// Fallback path (previous verified multi-kernel pipeline) — used only if the
// cooperative launch is rejected or the workspace is too small.
// ===========================================================================
__global__ void __launch_bounds__(256) stats_wconv_kernel(
    const float* __restrict__ x, float* __restrict__ stats,
    const float* __restrict__ w, unsigned short* __restrict__ Wb) {
    if (blockIdx.x >= 1024) {
        int idx = (blockIdx.x - 1024) * 256 + threadIdx.x;   // 32768 elements
        int i = idx & 63, o = (idx >> 6) & 63, k = idx >> 12;
        Wb[idx] = (unsigned short)f2bf(w[k * 4096 + i * 64 + o]);
        return;
    }
    const float4* x4 = (const float4*)x;
    int t = blockIdx.x * 256 + threadIdx.x;
    int stride = 1024 * 256;
    float4 s = {0.f, 0.f, 0.f, 0.f}, ss = {0.f, 0.f, 0.f, 0.f};
    for (int i = t; i < NV * (NC / 4); i += stride) {
        float4 v = x4[i];
        s.x += v.x; s.y += v.y; s.z += v.z; s.w += v.w;
        ss.x += v.x * v.x; ss.y += v.y * v.y; ss.z += v.z * v.z; ss.w += v.w * v.w;
    }
    __shared__ float4 ls[256], lss[256];
    ls[threadIdx.x] = s;
    lss[threadIdx.x] = ss;
    __syncthreads();
    if (threadIdx.x < 64) {
        int ch = threadIdx.x;
        int g = ch >> 2, comp = ch & 3;
        float a = 0.f, b = 0.f;
        #pragma unroll
        for (int k = 0; k < 16; ++k) {
            float4 v1 = ls[k * 16 + g];
            float4 v2 = lss[k * 16 + g];
            a += (comp == 0) ? v1.x : (comp == 1) ? v1.y : (comp == 2) ? v1.z : v1.w;
            b += (comp == 0) ? v2.x : (comp == 1) ? v2.y : (comp == 2) ? v2.z : v2.w;
        }
        atomicAdd(&stats[ch], a);
        atomicAdd(&stats[64 + ch], b);
    }
}

__global__ void __launch_bounds__(256) bn_mish_k0(
    const float* __restrict__ x, const float* __restrict__ stats,
    const float* __restrict__ gamma, const float* __restrict__ beta,
    unsigned short* __restrict__ dst) {
    int lane = threadIdx.x & 63;
    int wave = threadIdx.x >> 6;
    int c4 = lane & 15, rg = lane >> 4;
    int tile0 = blockIdx.x * TILE;

    float4 sc, sh;
    {
        float4 su = ((const float4*)stats)[c4];
        float4 sq = ((const float4*)stats)[16 + c4];
        float4 g4 = ((const float4*)gamma)[c4];
        float4 b4 = ((const float4*)beta)[c4];
        #define BNC(comp) { float mu = su.comp * (1.f / NV);                     \
                            float va = sq.comp * (1.f / NV) - mu * mu;           \
                            float rs = rsqrtf(va + EPS);                         \
                            sc.comp = g4.comp * rs;                              \
                            sh.comp = b4.comp - mu * sc.comp; }
        BNC(x) BNC(y) BNC(z) BNC(w)
        #undef BNC
    }

    const float4* x4 = (const float4*)x;
    #pragma unroll
    for (int it = 0; it < 4; ++it) {
        int v = tile0 + wave * 16 + it * 4 + rg;
        float4 h = x4[v * 16 + c4];
        float4 m;
        m.x = mish_f(h.x * sc.x + sh.x);
        m.y = mish_f(h.y * sc.y + sh.y);
        m.z = mish_f(h.z * sc.z + sh.z);
        m.w = mish_f(h.w * sc.w + sh.w);
        bf16x4 xb = { f2bf(m.x), f2bf(m.y), f2bf(m.z), f2bf(m.w) };
        *(bf16x4*)(dst + (size_t)v * NC + 4 * c4) = xb;
    }
}

template <bool FIRST>
__global__ void __launch_bounds__(256) cheb_step(
    const int* __restrict__ cols, const float* __restrict__ vals,
    const unsigned short* __restrict__ src, const unsigned short* __restrict__ prev,
    unsigned short* __restrict__ dst) {
    int lane = threadIdx.x & 63;
    int wave = threadIdx.x >> 6;
    int c8 = lane & 7, rg = lane >> 3;
    int tile0 = blockIdx.x * TILE;

    #pragma unroll
    for (int it = 0; it < 2; ++it) {
        int v = tile0 + wave * 16 + it * 8 + rg;
        const int* cp = cols + v * NDEG;
        const float* vp = vals + v * NDEG;
        i32x4u c03 = *(const i32x4u*)cp;
        i32x4u c47 = *(const i32x4u*)(cp + 4);
        int    cl8 = cp[8];
        f32x4u a03 = *(const f32x4u*)vp;
        f32x4u a47 = *(const f32x4u*)(vp + 4);
        float  al8 = vp[8];

        int   cj[NDEG] = { c03[0], c03[1], c03[2], c03[3],
                           c47[0], c47[1], c47[2], c47[3], cl8 };
        float aj[NDEG] = { a03[0], a03[1], a03[2], a03[3],
                           a47[0], a47[1], a47[2], a47[3], al8 };

        bf16x8 g[NDEG];
        #pragma unroll
        for (int j = 0; j < NDEG; ++j)
            g[j] = *(const bf16x8*)(src + (size_t)cj[j] * NC + c8 * 8);

        float s[8] = {0.f, 0.f, 0.f, 0.f, 0.f, 0.f, 0.f, 0.f};
        #pragma unroll
        for (int j = 0; j < NDEG; ++j)
            #pragma unroll
            for (int q = 0; q < 8; ++q) s[q] += aj[j] * bf2f(g[j][q]);

        bf16x8 xb;
        if (FIRST) {
            #pragma unroll
            for (int q = 0; q < 8; ++q) xb[q] = f2bf(s[q]);
        } else {
            bf16x8 p = __builtin_nontemporal_load(
                           (const bf16x8*)(prev + (size_t)v * NC + c8 * 8));
            #pragma unroll
            for (int q = 0; q < 8; ++q) xb[q] = f2bf(2.f * s[q] - bf2f(p[q]));
        }
        *(bf16x8*)(dst + (size_t)v * NC + c8 * 8) = xb;
    }
}

__global__ void __launch_bounds__(256) gemm_all(
    const unsigned short* __restrict__ basis, const unsigned short* __restrict__ Wb,
    const float* __restrict__ bias, float* __restrict__ out) {
    __shared__ short Al[2][NC * NC];
    __shared__ short Wl[2][NC * NC];

    const int tid  = threadIdx.x;
    const int lane = tid & 63;
    const int wave = tid >> 6;
    const int m16  = lane & 15, qq = lane >> 4;
    const int tile0 = blockIdx.x * TILE;
    const int rA = tid >> 3, cA = tid & 7;

    bf16x8 pa0, pa1, pw0, pw1;
    {
        const unsigned short* bp = basis + (size_t)(tile0 + rA) * NC + cA * 8;
        pa0 = __builtin_nontemporal_load((const bf16x8*)bp);
        pa1 = __builtin_nontemporal_load((const bf16x8*)(bp + 32 * NC));
        pw0 = *(const bf16x8*)(Wb + rA * NC + cA * 8);
        pw1 = *(const bf16x8*)(Wb + (rA + 32) * NC + cA * 8);
        *(bf16x8*)&Al[0][LDSOFF(rA, cA)] = pa0;
        *(bf16x8*)&Al[0][LDSOFF(rA + 32, cA)] = pa1;
        *(bf16x8*)&Wl[0][LDSOFF(rA, cA)] = pw0;
        *(bf16x8*)&Wl[0][LDSOFF(rA + 32, cA)] = pw1;
    }
    __syncthreads();

    f32x4 acc[4];
    #pragma unroll
    for (int nt = 0; nt < 4; ++nt) acc[nt] = (f32x4){0.f, 0.f, 0.f, 0.f};

    #pragma unroll
    for (int k = 0; k < NK; ++k) {
        if (k + 1 < NK) {
            const unsigned short* bp =
                basis + (size_t)(k + 1) * SLOT + (size_t)(tile0 + rA) * NC + cA * 8;
            pa0 = __builtin_nontemporal_load((const bf16x8*)bp);
            pa1 = __builtin_nontemporal_load((const bf16x8*)(bp + 32 * NC));
            const unsigned short* wp = Wb + (k + 1) * NC * NC;
            pw0 = *(const bf16x8*)(wp + rA * NC + cA * 8);
            pw1 = *(const bf16x8*)(wp + (rA + 32) * NC + cA * 8);
        }
        const short* ab = Al[k & 1];
        const short* wb = Wl[k & 1];
        bf16x8 a0 = *(const bf16x8*)&ab[LDSOFF(wave * 16 + m16, qq)];
        bf16x8 a1 = *(const bf16x8*)&ab[LDSOFF(wave * 16 + m16, qq + 4)];
        #pragma unroll
        for (int nt = 0; nt < 4; ++nt) {
            int o = nt * 16 + m16;
            bf16x8 b0 = *(const bf16x8*)&wb[LDSOFF(o, qq)];
            bf16x8 b1 = *(const bf16x8*)&wb[LDSOFF(o, qq + 4)];
            acc[nt] = __builtin_amdgcn_mfma_f32_16x16x32_bf16(a0, b0, acc[nt], 0, 0, 0);
            acc[nt] = __builtin_amdgcn_mfma_f32_16x16x32_bf16(a1, b1, acc[nt], 0, 0, 0);
        }
        if (k + 1 < NK) {
            short* an = Al[(k + 1) & 1];
            short* wn = Wl[(k + 1) & 1];
            *(bf16x8*)&an[LDSOFF(rA, cA)] = pa0;
            *(bf16x8*)&an[LDSOFF(rA + 32, cA)] = pa1;
            *(bf16x8*)&wn[LDSOFF(rA, cA)] = pw0;
            *(bf16x8*)&wn[LDSOFF(rA + 32, cA)] = pw1;
            __syncthreads();
        }
    }

    #pragma unroll
    for (int nt = 0; nt < 4; ++nt) {
        float bcol = bias[nt * 16 + m16];
        #pragma unroll
        for (int r = 0; r < 4; ++r) {
            int vout = tile0 + wave * 16 + qq * 4 + r;
            out[(size_t)vout * NC + nt * 16 + m16] = acc[nt][r] + bcol;
        }
    }
}

__global__ void __launch_bounds__(256) gemm_bases(
    const unsigned short* __restrict__ basis, const unsigned short* __restrict__ Wb,
    const float* __restrict__ bias, float* __restrict__ out,
    int kb, int kc, int S, int first) {
    int lane = threadIdx.x & 63;
    int wave = threadIdx.x >> 6;
    int m16 = lane & 15, qq = lane >> 4;
    int tile0 = blockIdx.x * TILE;

    f32x4 acc[4];
    #pragma unroll
    for (int nt = 0; nt < 4; ++nt) acc[nt] = (f32x4){0.f, 0.f, 0.f, 0.f};

    #pragma unroll 1
    for (int j = 0; j < kc; ++j) {
        int k = kb + j;
        const unsigned short* bs =
            basis + (size_t)(k % S) * SLOT + (size_t)(tile0 + wave * 16 + m16) * NC;
        bf16x8 a0 = *(const bf16x8*)(bs + qq * 8);
        bf16x8 a1 = *(const bf16x8*)(bs + 32 + qq * 8);
        const unsigned short* wk = Wb + (size_t)k * NC * NC;
        #pragma unroll
        for (int nt = 0; nt < 4; ++nt) {
            const unsigned short* wr = wk + (nt * 16 + m16) * NC;
            bf16x8 b0 = *(const bf16x8*)(wr + qq * 8);
            bf16x8 b1 = *(const bf16x8*)(wr + 32 + qq * 8);
            acc[nt] = __builtin_amdgcn_mfma_f32_16x16x32_bf16(a0, b0, acc[nt], 0, 0, 0);
            acc[nt] = __builtin_amdgcn_mfma_f32_16x16x32_bf16(a1, b1, acc[nt], 0, 0, 0);
        }
    }

    #pragma unroll
    for (int nt = 0; nt < 4; ++nt) {
        float bcol = bias[nt * 16 + m16];
        #pragma unroll
        for (int r = 0; r < 4; ++r) {
            int vout = tile0 + wave * 16 + qq * 4 + r;
            float* po = out + (size_t)vout * NC + nt * 16 + m16;
            *po = first ? (acc[nt][r] + bcol) : (*po + acc[nt][r]);
        }
    }
}

// ---------------------------------------------------------------------------
// ws: stats[128]f32 @0 | Wb bf16[8*64*64] @1 KiB | basis ring @128 KiB.
// Primary: single cooperative fused kernel (needs 7 basis slots).
// Fallback: prior verified multi-kernel pipeline.
// ---------------------------------------------------------------------------
extern "C" void kernel_launch(void* const* d_in, const int* in_sizes, int n_in,
                              void* d_out, int out_size, void* d_ws, size_t ws_size,
                              hipStream_t stream) {
    const float* x      = (const float*)d_in[0];
    const int*   cols   = (const int*)  d_in[2];
    const float* vals   = (const float*)d_in[3];
    const float* gamma  = (const float*)d_in[4];
    const float* beta   = (const float*)d_in[5];
    const float* weight = (const float*)d_in[6];
    const float* bias   = (const float*)d_in[7];
    float* out = (float*)d_out;

    char* wsb = (char*)d_ws;
    float*          stats = (float*)wsb;
    unsigned short* Wb    = (unsigned short*)(wsb + 1024);
    unsigned short* basis = (unsigned short*)(wsb + 131072);

    long long Sll = ((long long)ws_size - 131072) / (long long)(SLOT * sizeof(unsigned short));
    int S = (Sll < 0) ? 0 : (int)Sll;
    if (S > NK) S = NK;

    hipMemsetAsync(stats, 0, 1024, stream);

    if (S >= 7) {
        void* args[] = { (void*)&x, (void*)&cols, (void*)&vals, (void*)&gamma,
                         (void*)&beta, (void*)&weight, (void*)&bias,
                         (void*)&stats, (void*)&Wb, (void*)&basis, (void*)&out };
        hipError_t e = hipLaunchCooperativeKernel(
            reinterpret_cast<const void*>(&fused_cheb),
            dim3(FBLK), dim3(256), args, 0, stream);
        if (e == hipSuccess) return;
        (void)hipGetLastError();   // clear sticky error, fall through
    }

    // ---------------- fallback: previous verified pipeline ----------------
    if (S < 3) S = 3;
    stats_wconv_kernel<<<1152, 256, 0, stream>>>(x, stats, weight, Wb);
    bn_mish_k0<<<NBLK, 256, 0, stream>>>(x, stats, gamma, beta, basis);  // slot 0

    if (S >= NK) {
        for (int k = 1; k < NK; ++k) {
            const unsigned short* src = basis + (size_t)(k - 1) * SLOT;
            unsigned short*       dst = basis + (size_t)k * SLOT;
            if (k == 1) {
                cheb_step<true><<<NBLK, 256, 0, stream>>>(cols, vals, src, src, dst);
            } else {
                const unsigned short* prev = basis + (size_t)(k - 2) * SLOT;
                cheb_step<false><<<NBLK, 256, 0, stream>>>(cols, vals, src, prev, dst);
            }
        }
        gemm_all<<<NBLK, 256, 0, stream>>>(basis, Wb, bias, out);
    } else {
        int kb = 0, gsize = S, first = 1;
        while (kb < NK) {
            int kc = (gsize < NK - kb) ? gsize : (NK - kb);
            for (int k = (kb == 0 ? 1 : kb); k < kb + kc; ++k) {
                const unsigned short* src = basis + (size_t)((k - 1) % S) * SLOT;
                unsigned short*       dst = basis + (size_t)(k % S) * SLOT;
                if (k == 1) {
                    cheb_step<true><<<NBLK, 256, 0, stream>>>(cols, vals, src, src, dst);
                } else {
                    const unsigned short* prev = basis + (size_t)((k - 2) % S) * SLOT;
                    cheb_step<false><<<NBLK, 256, 0, stream>>>(cols, vals, src, prev, dst);
                }
            }
            gemm_bases<<<NBLK, 256, 0, stream>>>(basis, Wb, bias, out, kb, kc, S, first);
            first = 0;
            kb += kc;
            gsize = S - 2;
        }
    }
}

// Round 2
// 443.921 us; speedup vs baseline: 4.9195x; 4.9195x over previous
//
#include <hip/hip_runtime.h>
#include <math.h>

#define NV 196608
#define NDEG 9
#define NC 64
#define NK 8
#define TILE 64
#define NBLK (NV / TILE)   // 3072
#define SLOT ((size_t)NV * NC)
static constexpr float EPS = 1e-5f;

typedef __attribute__((ext_vector_type(8))) short bf16x8;
typedef __attribute__((ext_vector_type(4))) short bf16x4;
typedef __attribute__((ext_vector_type(4))) float f32x4;
typedef int   i32x4u __attribute__((ext_vector_type(4), aligned(4)));
typedef float f32x4u __attribute__((ext_vector_type(4), aligned(4)));

// float -> bf16 bits, round-to-nearest-even (finite inputs)
__device__ __forceinline__ short f2bf(float f) {
    unsigned u = __float_as_uint(f);
    unsigned r = (u + 0x7fffu + ((u >> 16) & 1u)) >> 16;
    return (short)r;
}
__device__ __forceinline__ float bf2f(short h) {
    return __uint_as_float(((unsigned)(unsigned short)h) << 16);
}

// exact mish: h * tanh(softplus(h)); tanh(ln(p)) = (p^2-1)/(p^2+1), p = 1+e^h
__device__ __forceinline__ float mish_f(float h) {
    float t = __expf(fminf(h, 20.f));
    float p = 1.f + t;
    float p2 = p * p;
    return h * ((p2 - 1.f) / (p2 + 1.f));
}

// LDS tile address: row-stride 64 shorts, 8-short chunks XOR-swizzled.
// Staging writes: 8 lanes x 16 B = exactly 32 banks per 8 lanes -> <=2-way (free).
// Fragment reads: measured 0 conflicts (round 6, prior session).
#define LDSOFF(r, c) ((r) * 64 + (((c) ^ ((r) & 7)) * 8))

// ---------------------------------------------------------------------------
// BN batch stats (blocks 0..1023) + W pre-transpose to bf16 (blocks 1024..1151).
// Wb[k][o][i] = bf16(weight[k][i][o]) -- exactly the MFMA B-fragment order.
// ---------------------------------------------------------------------------
__global__ void __launch_bounds__(256) stats_wconv_kernel(
    const float* __restrict__ x, float* __restrict__ stats,
    const float* __restrict__ w, unsigned short* __restrict__ Wb) {
    if (blockIdx.x >= 1024) {
        int idx = (blockIdx.x - 1024) * 256 + threadIdx.x;   // 32768 elements
        int i = idx & 63, o = (idx >> 6) & 63, k = idx >> 12;
        Wb[idx] = (unsigned short)f2bf(w[k * 4096 + i * 64 + o]);
        return;
    }
    const float4* x4 = (const float4*)x;
    int t = blockIdx.x * 256 + threadIdx.x;
    int stride = 1024 * 256;
    float4 s = {0.f, 0.f, 0.f, 0.f}, ss = {0.f, 0.f, 0.f, 0.f};
    for (int i = t; i < NV * (NC / 4); i += stride) {
        float4 v = x4[i];
        s.x += v.x; s.y += v.y; s.z += v.z; s.w += v.w;
        ss.x += v.x * v.x; ss.y += v.y * v.y; ss.z += v.z * v.z; ss.w += v.w * v.w;
    }
    __shared__ float4 ls[256], lss[256];
    ls[threadIdx.x] = s;
    lss[threadIdx.x] = ss;
    __syncthreads();
    if (threadIdx.x < 64) {
        int ch = threadIdx.x;
        int g = ch >> 2, comp = ch & 3;
        float a = 0.f, b = 0.f;
        #pragma unroll
        for (int k = 0; k < 16; ++k) {
            float4 v1 = ls[k * 16 + g];
            float4 v2 = lss[k * 16 + g];
            a += (comp == 0) ? v1.x : (comp == 1) ? v1.y : (comp == 2) ? v1.z : v1.w;
            b += (comp == 0) ? v2.x : (comp == 1) ? v2.y : (comp == 2) ? v2.z : v2.w;
        }
        atomicAdd(&stats[ch], a);
        atomicAdd(&stats[64 + ch], b);
    }
}

// ---------------------------------------------------------------------------
// k=0: BN apply + Mish -> basis slot 0 (bf16). Pure elementwise.
// ---------------------------------------------------------------------------
__global__ void __launch_bounds__(256) bn_mish_k0(
    const float* __restrict__ x, const float* __restrict__ stats,
    const float* __restrict__ gamma, const float* __restrict__ beta,
    unsigned short* __restrict__ dst) {
    int lane = threadIdx.x & 63;
    int wave = threadIdx.x >> 6;
    int c4 = lane & 15, rg = lane >> 4;
    int tile0 = blockIdx.x * TILE;

    float4 sc, sh;
    {
        float4 su = ((const float4*)stats)[c4];
        float4 sq = ((const float4*)stats)[16 + c4];
        float4 g4 = ((const float4*)gamma)[c4];
        float4 b4 = ((const float4*)beta)[c4];
        #define BNC(comp) { float mu = su.comp * (1.f / NV);                     \
                            float va = sq.comp * (1.f / NV) - mu * mu;           \
                            float rs = rsqrtf(va + EPS);                         \
                            sc.comp = g4.comp * rs;                              \
                            sh.comp = b4.comp - mu * sc.comp; }
        BNC(x) BNC(y) BNC(z) BNC(w)
        #undef BNC
    }

    const float4* x4 = (const float4*)x;
    #pragma unroll
    for (int it = 0; it < 4; ++it) {
        int v = tile0 + wave * 16 + it * 4 + rg;
        float4 h = x4[v * 16 + c4];
        float4 m;
        m.x = mish_f(h.x * sc.x + sh.x);
        m.y = mish_f(h.y * sc.y + sh.y);
        m.z = mish_f(h.z * sc.z + sh.z);
        m.w = mish_f(h.w * sc.w + sh.w);
        bf16x4 xb = { f2bf(m.x), f2bf(m.y), f2bf(m.z), f2bf(m.w) };
        *(bf16x4*)(dst + (size_t)v * NC + 4 * c4) = xb;
    }
}

// ---------------------------------------------------------------------------
// One Chebyshev step, bf16 in/out, fp32 arithmetic.
//   s = L @ src; dst = FIRST ? s : 2*s - prev.
// ---------------------------------------------------------------------------
template <bool FIRST>
__global__ void __launch_bounds__(256) cheb_step(
    const int* __restrict__ cols, const float* __restrict__ vals,
    const unsigned short* __restrict__ src, const unsigned short* __restrict__ prev,
    unsigned short* __restrict__ dst) {
    int lane = threadIdx.x & 63;
    int wave = threadIdx.x >> 6;
    int c8 = lane & 7, rg = lane >> 3;
    int tile0 = blockIdx.x * TILE;

    #pragma unroll
    for (int it = 0; it < 2; ++it) {
        int v = tile0 + wave * 16 + it * 8 + rg;
        const int* cp = cols + v * NDEG;
        const float* vp = vals + v * NDEG;
        i32x4u c03 = *(const i32x4u*)cp;
        i32x4u c47 = *(const i32x4u*)(cp + 4);
        int    cl8 = cp[8];
        f32x4u a03 = *(const f32x4u*)vp;
        f32x4u a47 = *(const f32x4u*)(vp + 4);
        float  al8 = vp[8];

        int   cj[NDEG] = { c03[0], c03[1], c03[2], c03[3],
                           c47[0], c47[1], c47[2], c47[3], cl8 };
        float aj[NDEG] = { a03[0], a03[1], a03[2], a03[3],
                           a47[0], a47[1], a47[2], a47[3], al8 };

        bf16x8 g[NDEG];
        #pragma unroll
        for (int j = 0; j < NDEG; ++j)
            g[j] = *(const bf16x8*)(src + (size_t)cj[j] * NC + c8 * 8);

        float s[8] = {0.f, 0.f, 0.f, 0.f, 0.f, 0.f, 0.f, 0.f};
        #pragma unroll
        for (int j = 0; j < NDEG; ++j)
            #pragma unroll
            for (int q = 0; q < 8; ++q) s[q] += aj[j] * bf2f(g[j][q]);

        bf16x8 xb;
        if (FIRST) {
            #pragma unroll
            for (int q = 0; q < 8; ++q) xb[q] = f2bf(s[q]);
        } else {
            bf16x8 p = __builtin_nontemporal_load(
                           (const bf16x8*)(prev + (size_t)v * NC + c8 * 8));
            #pragma unroll
            for (int q = 0; q < 8; ++q) xb[q] = f2bf(2.f * s[q] - bf2f(p[q]));
        }
        *(bf16x8*)(dst + (size_t)v * NC + c8 * 8) = xb;
    }
}

// ---------------------------------------------------------------------------
// FUSED final dispatch: Chebyshev step k=7 (slot 7 kept in LDS only, never
// written to global) + full einsum over k=0..7 with bias.
//   phase 1: x7 = 2*L@slot6 - slot5 for this block's 64 rows -> X7 (LDS)
//   phase 2: gemm_all structure; A-source k<7 = global slots, k=7 = X7.
// Saves: gemm_all dispatch + launch gap, 24 MB slot-7 write, 24 MB re-read.
// Prologue global loads are issued BEFORE the gather phase so the einsum
// staging rides in the gather-latency shadow.
// ---------------------------------------------------------------------------
__global__ void __launch_bounds__(256) cheb7_gemm(
    const int* __restrict__ cols, const float* __restrict__ vals,
    const unsigned short* __restrict__ basis, const unsigned short* __restrict__ Wb,
    const float* __restrict__ bias, float* __restrict__ out) {
    __shared__ __align__(16) short Al[2][NC * NC];   // 2 x 8 KB
    __shared__ __align__(16) short Wl[2][NC * NC];   // 2 x 8 KB
    __shared__ __align__(16) short X7[NC * NC];      // 8 KB (x7 tile)

    const int tid  = threadIdx.x;
    const int lane = tid & 63;
    const int wave = tid >> 6;
    const int c8 = lane & 7, rg = lane >> 3;         // cheb mapping
    const int m16 = lane & 15, qq = lane >> 4;       // MFMA fragment mapping
    const int tile0 = blockIdx.x * TILE;
    const int rA = tid >> 3, cA = tid & 7;           // staging mapping

    // ---- issue prologue (k=0) global loads first: independent of gathers ----
    bf16x8 pa0, pa1, pw0, pw1;
    {
        const unsigned short* bp = basis + (size_t)(tile0 + rA) * NC + cA * 8;
        pa0 = __builtin_nontemporal_load((const bf16x8*)bp);
        pa1 = __builtin_nontemporal_load((const bf16x8*)(bp + 32 * NC));
        pw0 = *(const bf16x8*)(Wb + rA * NC + cA * 8);
        pw1 = *(const bf16x8*)(Wb + (rA + 32) * NC + cA * 8);
    }

    // ---- phase 1: Chebyshev k=7 for own rows -> X7 (LDS), no global write ----
    {
        const unsigned short* src = basis + (size_t)6 * SLOT;
        const unsigned short* prv = basis + (size_t)5 * SLOT;
        #pragma unroll
        for (int it = 0; it < 2; ++it) {
            int r = wave * 16 + it * 8 + rg;
            int v = tile0 + r;
            const int* cp = cols + v * NDEG;
            const float* vp = vals + v * NDEG;
            i32x4u c03 = *(const i32x4u*)cp;
            i32x4u c47 = *(const i32x4u*)(cp + 4);
            int    cl8 = cp[8];
            f32x4u a03 = *(const f32x4u*)vp;
            f32x4u a47 = *(const f32x4u*)(vp + 4);
            float  al8 = vp[8];

            int   cj[NDEG] = { c03[0], c03[1], c03[2], c03[3],
                               c47[0], c47[1], c47[2], c47[3], cl8 };
            float aj[NDEG] = { a03[0], a03[1], a03[2], a03[3],
                               a47[0], a47[1], a47[2], a47[3], al8 };

            bf16x8 g[NDEG];
            #pragma unroll
            for (int j = 0; j < NDEG; ++j)
                g[j] = *(const bf16x8*)(src + (size_t)cj[j] * NC + c8 * 8);

            float s[8] = {0.f, 0.f, 0.f, 0.f, 0.f, 0.f, 0.f, 0.f};
            #pragma unroll
            for (int j = 0; j < NDEG; ++j)
                #pragma unroll
                for (int q = 0; q < 8; ++q) s[q] += aj[j] * bf2f(g[j][q]);

            // plain (cached) prev load: slot 5 rows are re-read by einsum k=5
            bf16x8 p = *(const bf16x8*)(prv + (size_t)v * NC + c8 * 8);
            bf16x8 xb;
            #pragma unroll
            for (int q = 0; q < 8; ++q) xb[q] = f2bf(2.f * s[q] - bf2f(p[q]));
            *(bf16x8*)&X7[LDSOFF(r, c8)] = xb;
        }
    }

    // ---- store prologue to LDS, then barrier (covers X7 as well) ----
    *(bf16x8*)&Al[0][LDSOFF(rA, cA)] = pa0;
    *(bf16x8*)&Al[0][LDSOFF(rA + 32, cA)] = pa1;
    *(bf16x8*)&Wl[0][LDSOFF(rA, cA)] = pw0;
    *(bf16x8*)&Wl[0][LDSOFF(rA + 32, cA)] = pw1;
    __syncthreads();

    // ---- phase 2: einsum k=0..7 (double-buffered; k=7 A-source = X7) ----
    f32x4 acc[4];
    #pragma unroll
    for (int nt = 0; nt < 4; ++nt) acc[nt] = (f32x4){0.f, 0.f, 0.f, 0.f};

    #pragma unroll
    for (int k = 0; k < NK; ++k) {
        if (k + 1 < NK) {
            if (k + 1 < NK - 1) {   // slot 7 comes from X7, no global A prefetch
                const unsigned short* bp =
                    basis + (size_t)(k + 1) * SLOT + (size_t)(tile0 + rA) * NC + cA * 8;
                pa0 = __builtin_nontemporal_load((const bf16x8*)bp);
                pa1 = __builtin_nontemporal_load((const bf16x8*)(bp + 32 * NC));
            }
            const unsigned short* wp = Wb + (k + 1) * NC * NC;
            pw0 = *(const bf16x8*)(wp + rA * NC + cA * 8);
            pw1 = *(const bf16x8*)(wp + (rA + 32) * NC + cA * 8);
        }
        const short* ab = (k < NK - 1) ? Al[k & 1] : X7;
        const short* wb = Wl[k & 1];
        bf16x8 a0 = *(const bf16x8*)&ab[LDSOFF(wave * 16 + m16, qq)];
        bf16x8 a1 = *(const bf16x8*)&ab[LDSOFF(wave * 16 + m16, qq + 4)];
        #pragma unroll
        for (int nt = 0; nt < 4; ++nt) {
            int o = nt * 16 + m16;
            bf16x8 b0 = *(const bf16x8*)&wb[LDSOFF(o, qq)];
            bf16x8 b1 = *(const bf16x8*)&wb[LDSOFF(o, qq + 4)];
            acc[nt] = __builtin_amdgcn_mfma_f32_16x16x32_bf16(a0, b0, acc[nt], 0, 0, 0);
            acc[nt] = __builtin_amdgcn_mfma_f32_16x16x32_bf16(a1, b1, acc[nt], 0, 0, 0);
        }
        if (k + 1 < NK) {
            if (k + 1 < NK - 1) {
                short* an = Al[(k + 1) & 1];
                *(bf16x8*)&an[LDSOFF(rA, cA)] = pa0;
                *(bf16x8*)&an[LDSOFF(rA + 32, cA)] = pa1;
            }
            short* wn = Wl[(k + 1) & 1];
            *(bf16x8*)&wn[LDSOFF(rA, cA)] = pw0;
            *(bf16x8*)&wn[LDSOFF(rA + 32, cA)] = pw1;
            __syncthreads();
        }
    }

    #pragma unroll
    for (int nt = 0; nt < 4; ++nt) {
        float bcol = bias[nt * 16 + m16];
        #pragma unroll
        for (int r = 0; r < 4; ++r) {
            int vout = tile0 + wave * 16 + qq * 4 + r;
            out[(size_t)vout * NC + nt * 16 + m16] = acc[nt][r] + bcol;
        }
    }
}

// ---------------------------------------------------------------------------
// Fallback einsum (small-ws path only): LDS-free grouped gemm.
// ---------------------------------------------------------------------------
__global__ void __launch_bounds__(256) gemm_bases(
    const unsigned short* __restrict__ basis, const unsigned short* __restrict__ Wb,
    const float* __restrict__ bias, float* __restrict__ out,
    int kb, int kc, int S, int first) {
    int lane = threadIdx.x & 63;
    int wave = threadIdx.x >> 6;
    int m16 = lane & 15, qq = lane >> 4;
    int tile0 = blockIdx.x * TILE;

    f32x4 acc[4];
    #pragma unroll
    for (int nt = 0; nt < 4; ++nt) acc[nt] = (f32x4){0.f, 0.f, 0.f, 0.f};

    #pragma unroll 1
    for (int j = 0; j < kc; ++j) {
        int k = kb + j;
        const unsigned short* bs =
            basis + (size_t)(k % S) * SLOT + (size_t)(tile0 + wave * 16 + m16) * NC;
        bf16x8 a0 = *(const bf16x8*)(bs + qq * 8);
        bf16x8 a1 = *(const bf16x8*)(bs + 32 + qq * 8);
        const unsigned short* wk = Wb + (size_t)k * NC * NC;
        #pragma unroll
        for (int nt = 0; nt < 4; ++nt) {
            const unsigned short* wr = wk + (nt * 16 + m16) * NC;
            bf16x8 b0 = *(const bf16x8*)(wr + qq * 8);
            bf16x8 b1 = *(const bf16x8*)(wr + 32 + qq * 8);
            acc[nt] = __builtin_amdgcn_mfma_f32_16x16x32_bf16(a0, b0, acc[nt], 0, 0, 0);
            acc[nt] = __builtin_amdgcn_mfma_f32_16x16x32_bf16(a1, b1, acc[nt], 0, 0, 0);
        }
    }

    #pragma unroll
    for (int nt = 0; nt < 4; ++nt) {
        float bcol = bias[nt * 16 + m16];
        #pragma unroll
        for (int r = 0; r < 4; ++r) {
            int vout = tile0 + wave * 16 + qq * 4 + r;
            float* po = out + (size_t)vout * NC + nt * 16 + m16;
            *po = first ? (acc[nt][r] + bcol) : (*po + acc[nt][r]);
        }
    }
}

// ---------------------------------------------------------------------------
// Inputs: (x, lap_rows, lap_cols, lap_vals, gamma, beta, weight, bias).
// lap_rows redundant (row-sorted, 9 nnz/row). cols delivered as int32.
// ws: stats[128]f32 @0 | Wb bf16[8*64*64] @1 KiB | basis ring @128 KiB.
// Primary path (S>=7): slots 0..6 materialized, slot 7 fused into final
// cheb7_gemm dispatch (LDS-only).
// ---------------------------------------------------------------------------
extern "C" void kernel_launch(void* const* d_in, const int* in_sizes, int n_in,
                              void* d_out, int out_size, void* d_ws, size_t ws_size,
                              hipStream_t stream) {
    const float* x      = (const float*)d_in[0];
    const int*   cols   = (const int*)  d_in[2];
    const float* vals   = (const float*)d_in[3];
    const float* gamma  = (const float*)d_in[4];
    const float* beta   = (const float*)d_in[5];
    const float* weight = (const float*)d_in[6];
    const float* bias   = (const float*)d_in[7];
    float* out = (float*)d_out;

    char* wsb = (char*)d_ws;
    float*          stats = (float*)wsb;
    unsigned short* Wb    = (unsigned short*)(wsb + 1024);
    unsigned short* basis = (unsigned short*)(wsb + 131072);

    long long Sll = ((long long)ws_size - 131072) / (long long)(SLOT * sizeof(unsigned short));
    int S = (Sll < 0) ? 0 : (int)Sll;
    if (S > NK) S = NK;
    if (S < 3) S = 3;

    hipMemsetAsync(stats, 0, 1024, stream);
    stats_wconv_kernel<<<1152, 256, 0, stream>>>(x, stats, weight, Wb);
    bn_mish_k0<<<NBLK, 256, 0, stream>>>(x, stats, gamma, beta, basis);  // slot 0

    if (S >= 7) {
        // slots 1..6 materialized; k=7 fused into the final gemm dispatch
        for (int k = 1; k < NK - 1; ++k) {
            const unsigned short* src = basis + (size_t)(k - 1) * SLOT;
            unsigned short*       dst = basis + (size_t)k * SLOT;
            if (k == 1) {
                cheb_step<true><<<NBLK, 256, 0, stream>>>(cols, vals, src, src, dst);
            } else {
                const unsigned short* prev = basis + (size_t)(k - 2) * SLOT;
                cheb_step<false><<<NBLK, 256, 0, stream>>>(cols, vals, src, prev, dst);
            }
        }
        cheb7_gemm<<<NBLK, 256, 0, stream>>>(cols, vals, basis, Wb, bias, out);
    } else {
        int kb = 0, gsize = S, first = 1;
        while (kb < NK) {
            int kc = (gsize < NK - kb) ? gsize : (NK - kb);
            for (int k = (kb == 0 ? 1 : kb); k < kb + kc; ++k) {
                const unsigned short* src = basis + (size_t)((k - 1) % S) * SLOT;
                unsigned short*       dst = basis + (size_t)(k % S) * SLOT;
                if (k == 1) {
                    cheb_step<true><<<NBLK, 256, 0, stream>>>(cols, vals, src, src, dst);
                } else {
                    const unsigned short* prev = basis + (size_t)((k - 2) % S) * SLOT;
                    cheb_step<false><<<NBLK, 256, 0, stream>>>(cols, vals, src, prev, dst);
                }
            }
            gemm_bases<<<NBLK, 256, 0, stream>>>(basis, Wb, bias, out, kb, kc, S, first);
            first = 0;
            kb += kc;
            gsize = S - 2;
        }
    }
}